// Round 1
// baseline (204.162 us; speedup 1.0000x reference)
//
#include <hip/hip_runtime.h>

#define IN_DIM   16384
#define OUT_DIM  16384
#define BATCH    64
#define K_IN     1024
#define K_OUT    1024
#define NPAIRS   (BATCH * K_OUT)   // 65536

// ---------------- prep kernels: build inverted CSR index row -> pairs -------

__global__ void zero_kernel(int* __restrict__ p, int n) {
    int i = blockIdx.x * blockDim.x + threadIdx.x;
    if (i < n) p[i] = 0;
}

__global__ void count_kernel(const int* __restrict__ out_idx,
                             int* __restrict__ counts) {
    int t = blockIdx.x * blockDim.x + threadIdx.x;
    atomicAdd(&counts[out_idx[t]], 1);
}

// single block, 256 threads, each owns 64 consecutive rows
__global__ void scan_kernel(const int* __restrict__ counts,
                            int* __restrict__ offsets) {
    __shared__ int partial[256];
    int t = threadIdx.x;
    int base = t * 64;
    int s = 0;
    for (int k = 0; k < 64; ++k) s += counts[base + k];
    partial[t] = s;
    __syncthreads();
    // Hillis-Steele inclusive scan (read; barrier; write; barrier)
    for (int off = 1; off < 256; off <<= 1) {
        int v = (t >= off) ? partial[t - off] : 0;
        __syncthreads();
        partial[t] += v;
        __syncthreads();
    }
    int excl = (t == 0) ? 0 : partial[t - 1];
    for (int k = 0; k < 64; ++k) {
        offsets[base + k] = excl;
        excl += counts[base + k];
    }
    if (t == 255) offsets[OUT_DIM] = excl;   // == NPAIRS
}

__global__ void scatter_kernel(const int* __restrict__ out_idx,
                               const int* __restrict__ offsets,
                               int* __restrict__ cursor,
                               int* __restrict__ pairs) {
    int t = blockIdx.x * blockDim.x + threadIdx.x;
    int r = out_idx[t];
    int pos = atomicAdd(&cursor[r], 1);
    pairs[offsets[r] + pos] = t;
}

// ---------------- main kernel: one block per W-row --------------------------
// Stage row into LDS (coalesced float4), then each wave computes one (b,j)
// dot product via LDS gathers + 64-lane shuffle reduction.

__launch_bounds__(256, 2)
__global__ void slide_main(const float* __restrict__ in_vals,
                           const float* __restrict__ W,
                           const float* __restrict__ bias,
                           const int*   __restrict__ in_idx,
                           const int*   __restrict__ offsets,
                           const int*   __restrict__ pairs,
                           float*       __restrict__ out) {
    __shared__ float row[IN_DIM];   // 64 KB
    int r   = blockIdx.x;
    int beg = offsets[r];
    int end = offsets[r + 1];
    if (beg == end) return;         // row never referenced: skip the 64 KB load

    // stage W[r, :] into LDS, coalesced 16 B/lane
    const float4* wrow = (const float4*)(W + (size_t)r * IN_DIM);
    float4*       lrow = (float4*)row;
    #pragma unroll
    for (int k = 0; k < 16; ++k) {
        int e = threadIdx.x + k * 256;
        lrow[e] = wrow[e];
    }
    __syncthreads();

    float bv   = bias[r];
    int   wave = threadIdx.x >> 6;
    int   lane = threadIdx.x & 63;

    for (int p = beg + wave; p < end; p += 4) {
        int t  = pairs[p];
        int bb = t >> 10;                     // batch
        const int*   idx = in_idx  + bb * K_IN;
        const float* val = in_vals + bb * K_IN;

        float acc = 0.f;
        #pragma unroll
        for (int i = 0; i < K_IN / 64; ++i) {
            int ii = lane + i * 64;           // coalesced idx/val loads (L2-hot)
            acc += row[idx[ii]] * val[ii];    // random-bank LDS gather
        }
        #pragma unroll
        for (int m = 32; m >= 1; m >>= 1) acc += __shfl_xor(acc, m, 64);
        if (lane == 0) out[t] = acc + bv;
    }
}

// ---------------------------------------------------------------------------

extern "C" void kernel_launch(void* const* d_in, const int* in_sizes, int n_in,
                              void* d_out, int out_size, void* d_ws, size_t ws_size,
                              hipStream_t stream) {
    const float* in_vals = (const float*)d_in[0];   // (64,1024) f32
    const float* W       = (const float*)d_in[1];   // (16384,16384) f32
    const float* bias    = (const float*)d_in[2];   // (16384,) f32
    const int*   in_idx  = (const int*)  d_in[3];   // (64,1024) i32
    const int*   out_idx = (const int*)  d_in[4];   // (64,1024) i32
    float*       out     = (float*)d_out;           // (64,1024) f32

    // workspace layout (ints): counts | cursor | offsets(+pad) | pairs
    int* counts  = (int*)d_ws;
    int* cursor  = counts + OUT_DIM;
    int* offsets = cursor + OUT_DIM;
    int* pairs   = offsets + OUT_DIM + 16;

    zero_kernel   <<<(2 * OUT_DIM + 255) / 256, 256, 0, stream>>>(counts, 2 * OUT_DIM);
    count_kernel  <<<NPAIRS / 256, 256, 0, stream>>>(out_idx, counts);
    scan_kernel   <<<1, 256, 0, stream>>>(counts, offsets);
    scatter_kernel<<<NPAIRS / 256, 256, 0, stream>>>(out_idx, offsets, cursor, pairs);
    slide_main    <<<OUT_DIM, 256, 0, stream>>>(in_vals, W, bias, in_idx, offsets, pairs, out);
}

// Round 2
// 194.899 us; speedup vs baseline: 1.0475x; 1.0475x over previous
//
#include <hip/hip_runtime.h>

#define IN_DIM   16384
#define OUT_DIM  16384
#define BATCH    64
#define K_IN     1024
#define K_OUT    1024
#define NPAIRS   (BATCH * K_OUT)   // 65536
#define CAP      64                // bucket capacity per row (P(overflow) ~ 1e-20)

// ---------------- prep: fixed-capacity bucket append ------------------------

__global__ void zero_kernel(int* __restrict__ p, int n) {
    int i = blockIdx.x * blockDim.x + threadIdx.x;
    if (i < n) p[i] = 0;
}

__global__ void scatter_kernel(const int* __restrict__ out_idx,
                               int* __restrict__ cursor,
                               int* __restrict__ pairs) {
    int t = blockIdx.x * blockDim.x + threadIdx.x;
    int r = out_idx[t];
    int pos = atomicAdd(&cursor[r], 1);
    if (pos < CAP) pairs[r * CAP + pos] = t;
}

// ---------------- main kernel: one block per W-row --------------------------
// Stage W[r,:] (64 KB) into LDS via async global_load_lds (width 16), then
// each wave computes one (b,j) pair's dot via LDS gathers + shuffle reduce.

__launch_bounds__(512)
__global__ void slide_main(const float* __restrict__ in_vals,
                           const float* __restrict__ W,
                           const float* __restrict__ bias,
                           const int*   __restrict__ in_idx,
                           const int*   __restrict__ cnts,
                           const int*   __restrict__ pairs,
                           float*       __restrict__ out) {
    __shared__ float row[IN_DIM];   // 64 KB -> 2 blocks/CU, 16 waves/CU
    int r   = blockIdx.x;
    int cnt = cnts[r];
    if (cnt == 0) return;           // unreferenced row: skip the 64 KB stream

    int w    = threadIdx.x >> 6;    // wave 0..7
    int lane = threadIdx.x & 63;

    // async stage: 8 waves x 8 issues x 1 KB = 64 KB, linear LDS layout
    const float* g = W + (size_t)r * IN_DIM;
    #pragma unroll
    for (int k = 0; k < 8; ++k) {
        int off = (k * 8 + w) * 256;                       // floats
        __builtin_amdgcn_global_load_lds(
            (const __attribute__((address_space(1))) void*)(g + off + lane * 4),
            (__attribute__((address_space(3))) void*)(row + off),
            16, 0, 0);
    }
    __syncthreads();                // drains vmcnt

    float bv = bias[r];
    const int* prow = pairs + (size_t)r * CAP;

    for (int p = w; p < cnt; p += 8) {
        int t  = prow[p];
        int bb = t >> 10;                                   // batch
        const int4*   idx4 = (const int4*)  (in_idx  + bb * K_IN);
        const float4* val4 = (const float4*)(in_vals + bb * K_IN);

        float acc = 0.f;
        #pragma unroll
        for (int i = 0; i < K_IN / 256; ++i) {              // 4 iters
            int4   id = idx4[lane + i * 64];                // coalesced, L2-hot
            float4 v  = val4[lane + i * 64];
            acc += row[id.x] * v.x + row[id.y] * v.y
                 + row[id.z] * v.z + row[id.w] * v.w;       // LDS gathers
        }
        #pragma unroll
        for (int m = 32; m >= 1; m >>= 1) acc += __shfl_xor(acc, m, 64);
        if (lane == 0) out[t] = acc + bv;
    }
}

// ---------------------------------------------------------------------------

extern "C" void kernel_launch(void* const* d_in, const int* in_sizes, int n_in,
                              void* d_out, int out_size, void* d_ws, size_t ws_size,
                              hipStream_t stream) {
    const float* in_vals = (const float*)d_in[0];   // (64,1024) f32
    const float* W       = (const float*)d_in[1];   // (16384,16384) f32
    const float* bias    = (const float*)d_in[2];   // (16384,) f32
    const int*   in_idx  = (const int*)  d_in[3];   // (64,1024) i32
    const int*   out_idx = (const int*)  d_in[4];   // (64,1024) i32
    float*       out     = (float*)d_out;           // (64,1024) f32

    // workspace (ints): cursor[OUT_DIM] | pairs[OUT_DIM*CAP]
    int* cursor = (int*)d_ws;
    int* pairs  = cursor + OUT_DIM;

    zero_kernel   <<<OUT_DIM / 256, 256, 0, stream>>>(cursor, OUT_DIM);
    scatter_kernel<<<NPAIRS / 256, 256, 0, stream>>>(out_idx, cursor, pairs);
    slide_main    <<<OUT_DIM, 512, 0, stream>>>(in_vals, W, bias, in_idx,
                                                cursor, pairs, out);
}